// Round 6
// baseline (491.527 us; speedup 1.0000x reference)
//
#include <hip/hip_runtime.h>

// Problem constants (fixed by the reference).
constexpr int N = 100000;   // nodes
constexpr int E = 1600000;  // edges
constexpr int D = 128;      // feature dim (both layers)
constexpr int M = 5000;     // mask size

constexpr int SCHUNK = 1024;                       // scan elements per block
constexpr int SBLK = (N + SCHUNK - 1) / SCHUNK;    // 98 scan blocks

constexpr int GEMM_BLKS  = N / 16;                 // 6250 (16 rows/block)
constexpr int BUILD_BLKS = E / 256;                // 6250 (E divisible by 256)

// ---------------- bf16 helpers (RNE pack, cheap unpack) ----------------

__device__ __forceinline__ unsigned int pack_bf16x2(float a, float b) {
    unsigned int ua = __float_as_uint(a);
    unsigned int ub = __float_as_uint(b);
    ua = (ua + 0x7FFFu + ((ua >> 16) & 1u)) >> 16;
    ub = (ub + 0x7FFFu + ((ub >> 16) & 1u)) & 0xFFFF0000u;
    return ua | ub;
}
__device__ __forceinline__ float bf16_lo(unsigned int u) { return __uint_as_float(u << 16); }
__device__ __forceinline__ float bf16_hi(unsigned int u) { return __uint_as_float(u & 0xFFFF0000u); }

// ---------------- GEMM body: 16 rows/block, 256 thr; thread = col-pair x 4 rows ----------------
// Output packed bf16 (uint = 2 cols). Input f32 (layer 1) or bf16 (layer 2).

template <bool BF16IN>
__device__ __forceinline__ void gemm_body(const void* __restrict__ Xin,
                                          const float* __restrict__ W,
                                          unsigned int* __restrict__ Hb, int blk) {
    __shared__ float Xs[16 * D];
    const int t = threadIdx.x;
    const int p = t & 63;    // col pair: cols {2p, 2p+1}
    const int rg = t >> 6;   // row group 0..3 (rows rg*4 .. rg*4+3)
    const int row0 = blk * 16;

    if (BF16IN) {
        const uint4* Xu = (const uint4*)((const unsigned int*)Xin + (size_t)row0 * 64);
        uint4 u = Xu[t];  // 1024 uints total, 4 per thread
        float4* Xs4 = (float4*)Xs;
        Xs4[2 * t]     = make_float4(bf16_lo(u.x), bf16_hi(u.x), bf16_lo(u.y), bf16_hi(u.y));
        Xs4[2 * t + 1] = make_float4(bf16_lo(u.z), bf16_hi(u.z), bf16_lo(u.w), bf16_hi(u.w));
    } else {
        const float4* Xf = (const float4*)((const float*)Xin + (size_t)row0 * D);
        float4* Xs4 = (float4*)Xs;
        Xs4[t]       = Xf[t];
        Xs4[t + 256] = Xf[t + 256];
    }
    __syncthreads();

    float acc[4][2] = {};
#pragma unroll 4
    for (int kk = 0; kk < D; kk += 4) {
        float2 w0 = *(const float2*)(W + (kk + 0) * D + 2 * p);
        float2 w1 = *(const float2*)(W + (kk + 1) * D + 2 * p);
        float2 w2 = *(const float2*)(W + (kk + 2) * D + 2 * p);
        float2 w3 = *(const float2*)(W + (kk + 3) * D + 2 * p);
#pragma unroll
        for (int r = 0; r < 4; ++r) {
            float4 xv = *(const float4*)(Xs + (rg * 4 + r) * D + kk);
            acc[r][0] = fmaf(xv.w, w3.x, fmaf(xv.z, w2.x, fmaf(xv.y, w1.x, fmaf(xv.x, w0.x, acc[r][0]))));
            acc[r][1] = fmaf(xv.w, w3.y, fmaf(xv.z, w2.y, fmaf(xv.y, w1.y, fmaf(xv.x, w0.y, acc[r][1]))));
        }
    }
#pragma unroll
    for (int r = 0; r < 4; ++r)
        Hb[(size_t)(row0 + rg * 4 + r) * 64 + p] = pack_bf16x2(acc[r][0], acc[r][1]);
}

// ---------------- fused: GEMM1 (x f32 -> A bf16)  +  CSR build (u64 atomics) ----------------
// packed[d]: bits[47:0] = sum(ew*2^30) fixed point, bits[63:48] = count.
// Returned old value's count field = edge's rank within its dst bucket.

__global__ __launch_bounds__(256) void k_fused1(const float* __restrict__ x,
                                                const float* __restrict__ W1,
                                                unsigned int* __restrict__ A,
                                                const int* __restrict__ dst,
                                                const float* __restrict__ ew,
                                                unsigned long long* __restrict__ packed,
                                                int* __restrict__ rank) {
    if (blockIdx.x < GEMM_BLKS) {
        gemm_body<false>(x, W1, A, blockIdx.x);
    } else {
        int e = (blockIdx.x - GEMM_BLKS) * 256 + threadIdx.x;  // exact: E = 6250*256
        int d = dst[e];
        unsigned long long val =
            (1ull << 48) | (unsigned long long)(ew[e] * 1073741824.0f + 0.5f);
        unsigned long long old = atomicAdd(&packed[d], val);
        rank[e] = (int)(old >> 48);
    }
}

__global__ __launch_bounds__(256) void k_gemm2(const unsigned int* __restrict__ B,
                                               const float* __restrict__ W2,
                                               unsigned int* __restrict__ A2) {
    gemm_body<true>(B, W2, A2, blockIdx.x);
}

// ---------------- unpack: dis = rsqrt(1 + frac*2^-30), count = hi16 ----------------

__global__ void k_unpack(const unsigned long long* __restrict__ packed,
                         float* __restrict__ dis, int* __restrict__ count) {
    int i = blockIdx.x * 256 + threadIdx.x;
    if (i >= N) return;
    unsigned long long p = packed[i];
    count[i] = (int)(p >> 48);
    float deg = 1.0f + (float)((double)(p & 0xFFFFFFFFFFFFull) * (1.0 / 1073741824.0));
    dis[i] = rsqrtf(deg);
}

// ---------------- parallel scan (3 phases) ----------------

__global__ __launch_bounds__(256) void k_scan_partial(const int* __restrict__ count,
                                                      int* __restrict__ blockSums) {
    __shared__ int ws_[4];
    const int t = threadIdx.x;
    const int idx = blockIdx.x * SCHUNK + t * 4;
    int s = 0;
    if (idx + 3 < N) {
        int4 c = *(const int4*)(count + idx);
        s = c.x + c.y + c.z + c.w;
    } else {
        for (int i = 0; i < 4; ++i) if (idx + i < N) s += count[idx + i];
    }
    for (int off = 32; off > 0; off >>= 1) s += __shfl_down(s, off);
    if ((t & 63) == 0) ws_[t >> 6] = s;
    __syncthreads();
    if (t == 0) blockSums[blockIdx.x] = ws_[0] + ws_[1] + ws_[2] + ws_[3];
}

__global__ __launch_bounds__(128) void k_scan_blocksums(int* __restrict__ blockSums,
                                                        int* __restrict__ blockOff,
                                                        int* __restrict__ rowStart) {
    __shared__ int sh[128];
    int t = threadIdx.x;
    int v = (t < SBLK) ? blockSums[t] : 0;
    sh[t] = v;
    __syncthreads();
    for (int off = 1; off < 128; off <<= 1) {
        int u = (t >= off) ? sh[t - off] : 0;
        __syncthreads();
        sh[t] += u;
        __syncthreads();
    }
    if (t < SBLK) blockOff[t] = sh[t] - v;  // exclusive
    if (t == 0) rowStart[N] = E;
}

__global__ __launch_bounds__(256) void k_scan_final(const int* __restrict__ count,
                                                    const int* __restrict__ blockOff,
                                                    int* __restrict__ rowStart) {
    __shared__ int waveS[4];
    const int t = threadIdx.x;
    const int lane = t & 63;
    const int wave = t >> 6;
    const int idx = blockIdx.x * SCHUNK + t * 4;

    int4 c = make_int4(0, 0, 0, 0);
    if (idx + 3 < N) c = *(const int4*)(count + idx);
    else {
        if (idx + 0 < N) c.x = count[idx + 0];
        if (idx + 1 < N) c.y = count[idx + 1];
        if (idx + 2 < N) c.z = count[idx + 2];
        if (idx + 3 < N) c.w = count[idx + 3];
    }
    int s = c.x + c.y + c.z + c.w;

    int v = s;
    for (int off = 1; off < 64; off <<= 1) {
        int u = __shfl_up(v, off);
        if (lane >= off) v += u;
    }
    if (lane == 63) waveS[wave] = v;
    __syncthreads();
    int waveBase = 0;
    for (int w = 0; w < 4; ++w) if (w < wave) waveBase += waveS[w];
    int excl = blockOff[blockIdx.x] + waveBase + (v - s);

    int4 rs;
    rs.x = excl;
    rs.y = excl + c.x;
    rs.z = excl + c.x + c.y;
    rs.w = excl + c.x + c.y + c.z;
    if (idx + 3 < N) {
        *(int4*)(rowStart + idx) = rs;
    } else {
        if (idx + 0 < N) rowStart[idx + 0] = rs.x;
        if (idx + 1 < N) rowStart[idx + 1] = rs.y;
        if (idx + 2 < N) rowStart[idx + 2] = rs.z;
        if (idx + 3 < N) rowStart[idx + 3] = rs.w;
    }
}

// ---------------- fill (NO atomics): pairs[rowStart[d]+rank] = (src, dis[src]*ew) ----------------

__global__ void k_fill(const int* __restrict__ src, const int* __restrict__ dst,
                       const float* __restrict__ ew, const float* __restrict__ dis,
                       const int* __restrict__ rowStart, const int* __restrict__ rank,
                       int2* __restrict__ pairs) {
    int e = blockIdx.x * 256 + threadIdx.x;
    if (e >= E) return;
    int s = src[e], d = dst[e];
    int pos = rowStart[d] + rank[e];
    float v = dis[s] * ew[e];
    pairs[pos] = make_int2(s, __float_as_int(v));
}

// ---------------- aggregate layer 1: B = relu(dis*sum + A/deg + b1), bf16 in/out ----------------
// One wave per node; lane owns a col-pair (one uint = 2 bf16).

__global__ __launch_bounds__(256) void k_aggregate(const unsigned int* __restrict__ Hb,
                                                   const int2* __restrict__ pairs,
                                                   const int* __restrict__ rowStart,
                                                   const float* __restrict__ dis,
                                                   const float* __restrict__ b,
                                                   unsigned int* __restrict__ outB) {
    int node = blockIdx.x * 4 + (threadIdx.x >> 6);
    if (node >= N) return;
    int lane = threadIdx.x & 63;
    int beg = rowStart[node], end = rowStart[node + 1];

    float ax = 0.f, ay = 0.f;
    int j = beg;
    for (; j + 3 < end; j += 4) {  // 4 gathers in flight
        int2 p0 = pairs[j], p1 = pairs[j + 1], p2 = pairs[j + 2], p3 = pairs[j + 3];
        unsigned int h0 = Hb[(size_t)p0.x * 64 + lane];
        unsigned int h1 = Hb[(size_t)p1.x * 64 + lane];
        unsigned int h2 = Hb[(size_t)p2.x * 64 + lane];
        unsigned int h3 = Hb[(size_t)p3.x * 64 + lane];
        float v0 = __int_as_float(p0.y), v1 = __int_as_float(p1.y);
        float v2 = __int_as_float(p2.y), v3 = __int_as_float(p3.y);
        ax += bf16_lo(h0) * v0 + bf16_lo(h1) * v1 + bf16_lo(h2) * v2 + bf16_lo(h3) * v3;
        ay += bf16_hi(h0) * v0 + bf16_hi(h1) * v1 + bf16_hi(h2) * v2 + bf16_hi(h3) * v3;
    }
    for (; j < end; ++j) {
        int2 p0 = pairs[j];
        unsigned int h0 = Hb[(size_t)p0.x * 64 + lane];
        float v0 = __int_as_float(p0.y);
        ax += bf16_lo(h0) * v0;
        ay += bf16_hi(h0) * v0;
    }

    float dd = dis[node];
    float sn = dd * dd;  // self-loop norm = 1/deg
    unsigned int hs = Hb[(size_t)node * 64 + lane];
    float2 bb = ((const float2*)b)[lane];
    float ox = fmaxf(ax * dd + bf16_lo(hs) * sn + bb.x, 0.f);
    float oy = fmaxf(ay * dd + bf16_hi(hs) * sn + bb.y, 0.f);
    outB[(size_t)node * 64 + lane] = pack_bf16x2(ox, oy);
}

// ---------------- layer-2 aggregate at mask nodes only -> d_out (f32 rows + y) ----------------

__global__ __launch_bounds__(256) void k_aggregate_mask(const unsigned int* __restrict__ Hb,
                                                        const int2* __restrict__ pairs,
                                                        const int* __restrict__ rowStart,
                                                        const float* __restrict__ dis,
                                                        const float* __restrict__ b,
                                                        const int* __restrict__ mask,
                                                        const int* __restrict__ y,
                                                        float* __restrict__ out) {
    int i = blockIdx.x * 4 + (threadIdx.x >> 6);
    if (i >= M) return;
    int lane = threadIdx.x & 63;
    int node = mask[i];
    int beg = rowStart[node], end = rowStart[node + 1];

    float ax = 0.f, ay = 0.f;
    int j = beg;
    for (; j + 3 < end; j += 4) {
        int2 p0 = pairs[j], p1 = pairs[j + 1], p2 = pairs[j + 2], p3 = pairs[j + 3];
        unsigned int h0 = Hb[(size_t)p0.x * 64 + lane];
        unsigned int h1 = Hb[(size_t)p1.x * 64 + lane];
        unsigned int h2 = Hb[(size_t)p2.x * 64 + lane];
        unsigned int h3 = Hb[(size_t)p3.x * 64 + lane];
        float v0 = __int_as_float(p0.y), v1 = __int_as_float(p1.y);
        float v2 = __int_as_float(p2.y), v3 = __int_as_float(p3.y);
        ax += bf16_lo(h0) * v0 + bf16_lo(h1) * v1 + bf16_lo(h2) * v2 + bf16_lo(h3) * v3;
        ay += bf16_hi(h0) * v0 + bf16_hi(h1) * v1 + bf16_hi(h2) * v2 + bf16_hi(h3) * v3;
    }
    for (; j < end; ++j) {
        int2 p0 = pairs[j];
        unsigned int h0 = Hb[(size_t)p0.x * 64 + lane];
        float v0 = __int_as_float(p0.y);
        ax += bf16_lo(h0) * v0;
        ay += bf16_hi(h0) * v0;
    }

    float dd = dis[node];
    float sn = dd * dd;
    unsigned int hs = Hb[(size_t)node * 64 + lane];
    float2 bb = ((const float2*)b)[lane];
    float ox = ax * dd + bf16_lo(hs) * sn + bb.x;
    float oy = ay * dd + bf16_hi(hs) * sn + bb.y;
    ((float2*)(out + (size_t)i * D))[lane] = make_float2(ox, oy);
    if (lane == 0) out[(size_t)M * D + i] = (float)y[node];
}

extern "C" void kernel_launch(void* const* d_in, const int* in_sizes, int n_in,
                              void* d_out, int out_size, void* d_ws, size_t ws_size,
                              hipStream_t stream) {
    const float* x  = (const float*)d_in[0];
    const float* ew = (const float*)d_in[1];
    const float* W1 = (const float*)d_in[2];
    const float* b1 = (const float*)d_in[3];
    const float* W2 = (const float*)d_in[4];
    const float* b2 = (const float*)d_in[5];
    const int* eidx = (const int*)d_in[6];
    const int* mask = (const int*)d_in[7];
    const int* y    = (const int*)d_in[8];
    const int* src = eidx;       // edge_index[0]
    const int* dst = eidx + E;   // edge_index[1]

    // Workspace layout (bytes):
    //   packed    @ 0        : N u64            (0.8 MB)
    //   dis       @ 1.0 MB   : N f32            (0.4 MB)
    //   count     @ 1.5 MB   : N i32            (0.4 MB)
    //   rowStart  @ 2.0 MB   : N+1 i32          (0.4 MB)
    //   blockSums @ 2.5 MB   : SBLK i32
    //   blockOff  @ 2.5 MB+4K: SBLK i32
    //   pairs     @ 3.0 MB   : E int2           (12.8 MB)
    //   rank      @ 16 MB    : E i32            (6.4 MB)
    //   A  (bf16) @ 24 MB    : N*D bf16         (25.6 MB)
    //   B  (bf16) @ 50 MB    : N*D bf16         (25.6 MB)
    //   A2 (bf16) @ 76 MB    : N*D bf16         (25.6 MB)   total ~101.6 MB
    char* ws = (char*)d_ws;
    unsigned long long* packed = (unsigned long long*)(ws);
    float* dis      = (float*)(ws + (size_t)1024 * 1024);
    int*   count    = (int*)(ws + (size_t)1536 * 1024);
    int*   rowStart = (int*)(ws + (size_t)2048 * 1024);
    int*   blockSums= (int*)(ws + (size_t)2560 * 1024);
    int*   blockOff = (int*)(ws + (size_t)2560 * 1024 + 4096);
    int2*  pairs    = (int2*)(ws + (size_t)3072 * 1024);
    int*   rank     = (int*)(ws + (size_t)16 * 1024 * 1024);
    unsigned int* A  = (unsigned int*)(ws + (size_t)24 * 1024 * 1024);
    unsigned int* B  = (unsigned int*)(ws + (size_t)50 * 1024 * 1024);
    unsigned int* A2 = (unsigned int*)(ws + (size_t)76 * 1024 * 1024);

    // --- fused: GEMM1 + CSR build (independent; overlap atomics with compute) ---
    (void)hipMemsetAsync(packed, 0, (size_t)N * sizeof(unsigned long long), stream);
    hipLaunchKernelGGL(k_fused1, dim3(GEMM_BLKS + BUILD_BLKS), dim3(256), 0, stream,
                       x, W1, A, dst, ew, packed, rank);

    // --- normalization + CSR finalize ---
    hipLaunchKernelGGL(k_unpack, dim3((N + 255) / 256), dim3(256), 0, stream, packed, dis, count);
    hipLaunchKernelGGL(k_scan_partial, dim3(SBLK), dim3(256), 0, stream, count, blockSums);
    hipLaunchKernelGGL(k_scan_blocksums, dim3(1), dim3(128), 0, stream, blockSums, blockOff, rowStart);
    hipLaunchKernelGGL(k_scan_final, dim3(SBLK), dim3(256), 0, stream, count, blockOff, rowStart);
    hipLaunchKernelGGL(k_fill, dim3((E + 255) / 256), dim3(256), 0, stream,
                       src, dst, ew, dis, rowStart, rank, pairs);

    // --- layer 1 aggregate: B = relu(agg(A) + b1)  [bf16 -> bf16] ---
    hipLaunchKernelGGL(k_aggregate, dim3((N + 3) / 4), dim3(256), 0, stream,
                       A, pairs, rowStart, dis, b1, B);

    // --- layer 2: A2 = B@W2 (bf16) ; out = agg(A2) at mask nodes ---
    hipLaunchKernelGGL(k_gemm2, dim3(GEMM_BLKS), dim3(256), 0, stream, B, W2, A2);
    hipLaunchKernelGGL(k_aggregate_mask, dim3((M + 3) / 4), dim3(256), 0, stream,
                       A2, pairs, rowStart, dis, b2, mask, y, (float*)d_out);
}